// Round 10
// baseline (228.883 us; speedup 1.0000x reference)
//
#include <hip/hip_runtime.h>

#define BB   4
#define QS   512
#define KSZ  1024
#define DD   512
#define HH   128
#define DVV  512

typedef unsigned int uint;
typedef unsigned short ushort;
typedef __attribute__((ext_vector_type(8)))  short short8;   // 8 bf16 (4 VGPRs)
typedef __attribute__((ext_vector_type(16))) float f32x16;   // MFMA 32x32 acc

__device__ __forceinline__ float rcp_fast(float x)  { return __builtin_amdgcn_rcpf(x); }
__device__ __forceinline__ float exp2_fast(float x) { return __builtin_amdgcn_exp2f(x); }

// split fp32 -> bf16 hi (truncate) + bf16 lo (residual); ~2^-17 rel combined
__device__ __forceinline__ void split1(float v, ushort& h, ushort& l) {
    uint u = __float_as_uint(v);
    h = (ushort)(u >> 16);
    float r = v - __uint_as_float(u & 0xffff0000u);
    l = (ushort)(__float_as_uint(r) >> 16);
}

// split_kernel grid segments (q/k/W only; V^T lives in projvt_kernel)
#define NSQ  (BB * QS * DD / 4 / 256)     // 1024
#define NSK  (BB * KSZ * DD / 4 / 256)    // 2048
#define NWT  128                          // 64 per W
#define NPJ  192                          // proj blocks (768 waves)
#define NVT  (BB * (KSZ / 32) * (DVV / 32))  // 2048 V-transpose blocks

// ---------------------------------------------------------------------------
// Kernel 1: bf16 pre-split of q, k (element-wise) and W_q/W_k (transpose to
// [h][d]). Pure memory-bound, ~25 MB.
// ---------------------------------------------------------------------------
__global__ __launch_bounds__(256) void split_kernel(
    const float* __restrict__ q, const float* __restrict__ k,
    const float* __restrict__ Wq, const float* __restrict__ Wk,
    ushort* __restrict__ qh, ushort* __restrict__ ql,
    ushort* __restrict__ kh, ushort* __restrict__ kl,
    ushort* __restrict__ wqh, ushort* __restrict__ wql,
    ushort* __restrict__ wkh, ushort* __restrict__ wkl)
{
    const int id  = blockIdx.x;
    const int tid = threadIdx.x;

    if (id < NSQ + NSK) {
        const float* src; ushort* dh; ushort* dl; size_t i;
        if (id < NSQ) { src = q; dh = qh; dl = ql; i = (size_t)id * 256 + tid; }
        else          { src = k; dh = kh; dl = kl; i = (size_t)(id - NSQ) * 256 + tid; }
        float4 v = ((const float4*)src)[i];
        ushort h0,h1,h2,h3,l0,l1,l2,l3;
        split1(v.x,h0,l0); split1(v.y,h1,l1); split1(v.z,h2,l2); split1(v.w,h3,l3);
        *(ushort4*)&dh[i * 4] = make_ushort4(h0,h1,h2,h3);
        *(ushort4*)&dl[i * 4] = make_ushort4(l0,l1,l2,l3);
        return;
    }
    // ---- W transpose + split: [512][128] -> [128][512] hi/lo ----
    __shared__ float Ts[32][33];
    int t = id - (NSQ + NSK);
    const float* W; ushort* dh; ushort* dl;
    if (t < 64) { W = Wq; dh = wqh; dl = wql; }
    else        { W = Wk; dh = wkh; dl = wkl; t -= 64; }
    const int d0 = (t >> 2) * 32, h0 = (t & 3) * 32;
    {
        const int dd = tid >> 3, c4 = (tid & 7) * 4;
        float4 v = *(const float4*)&W[(size_t)(d0 + dd) * HH + h0 + c4];
        Ts[dd][c4 + 0] = v.x; Ts[dd][c4 + 1] = v.y;
        Ts[dd][c4 + 2] = v.z; Ts[dd][c4 + 3] = v.w;
    }
    __syncthreads();
    {
        const int hh = tid >> 3, d4 = (tid & 7) * 4;
        ushort h[4], l[4];
        #pragma unroll
        for (int i = 0; i < 4; i++) split1(Ts[d4 + i][hh], h[i], l[i]);
        size_t o = (size_t)(h0 + hh) * DD + d0 + d4;
        *(ushort4*)&dh[o] = make_ushort4(h[0], h[1], h[2], h[3]);
        *(ushort4*)&dl[o] = make_ushort4(l[0], l[1], l[2], l[3]);
    }
}

// ---------------------------------------------------------------------------
// Kernel 2 (fused): blocks [0,NPJ) = projection via MFMA (pre-split bf16
// operands, b128 loads, 3 MFMAs/k16) + exp(2x). Blocks [NPJ,+NVT) = V
// transpose+split (memory-bound backfill behind proj's 192-block tail).
// ---------------------------------------------------------------------------
__global__ __launch_bounds__(256) void projvt_kernel(
    const ushort* __restrict__ qh, const ushort* __restrict__ ql,
    const ushort* __restrict__ kh, const ushort* __restrict__ kl,
    const ushort* __restrict__ wqh, const ushort* __restrict__ wql,
    const ushort* __restrict__ wkh, const ushort* __restrict__ wkl,
    const float* __restrict__ val,
    float* __restrict__ eq, float* __restrict__ ek,
    ushort* __restrict__ vhi, ushort* __restrict__ vlo)
{
    const int id  = blockIdx.x;
    const int tid = threadIdx.x;

    if (id >= NPJ) {
        __shared__ float Ts[32][33];
        const int t   = id - NPJ;
        const int b   = t >> 9;
        const int rem = t & 511;
        const int k0  = (rem >> 4) * 32;
        const int n0  = (rem & 15) * 32;
        {
            const int kk = tid >> 3, n4 = (tid & 7) * 4;
            float4 v = *(const float4*)&val[((size_t)b * KSZ + k0 + kk) * DVV + n0 + n4];
            Ts[kk][n4 + 0] = v.x; Ts[kk][n4 + 1] = v.y;
            Ts[kk][n4 + 2] = v.z; Ts[kk][n4 + 3] = v.w;
        }
        __syncthreads();
        {
            const int nn = tid >> 3, k4 = (tid & 7) * 4;
            ushort h[4], l[4];
            #pragma unroll
            for (int i = 0; i < 4; i++) split1(Ts[k4 + i][nn], h[i], l[i]);
            size_t o = ((size_t)b * DVV + n0 + nn) * KSZ + k0 + k4;
            *(ushort4*)&vhi[o] = make_ushort4(h[0], h[1], h[2], h[3]);
            *(ushort4*)&vlo[o] = make_ushort4(l[0], l[1], l[2], l[3]);
        }
        return;
    }

    // ---- projection: eq/ek[m][h] = exp2(C2L * sum_d A[m][d]*W[d][h]) ----
    const int w = tid >> 6, lane = tid & 63;
    const int row = lane & 31, kg = lane >> 5;
    const int gw = id * 4 + w;                  // 0..767

    const ushort *pa_h, *pa_l, *pb_h, *pb_l; float* op; int m0, nt;
    if (gw < 256) {
        m0 = (gw >> 2) * 32; nt = gw & 3;
        pa_h = qh; pa_l = ql; pb_h = wqh; pb_l = wql; op = eq;
    } else {
        const int g = gw - 256;
        m0 = (g >> 2) * 32; nt = g & 3;
        pa_h = kh; pa_l = kl; pb_h = wkh; pb_l = wkl; op = ek;
    }

    const ushort* ah_p = pa_h + (size_t)(m0 + row) * DD + kg * 8;
    const ushort* al_p = pa_l + (size_t)(m0 + row) * DD + kg * 8;
    const ushort* bh_p = pb_h + (size_t)(nt * 32 + row) * DD + kg * 8;
    const ushort* bl_p = pb_l + (size_t)(nt * 32 + row) * DD + kg * 8;

    f32x16 acc;
    #pragma unroll
    for (int i = 0; i < 16; i++) acc[i] = 0.f;

    #pragma unroll 8
    for (int ks = 0; ks < DD; ks += 16) {
        short8 ah = *(const short8*)(ah_p + ks);
        short8 al = *(const short8*)(al_p + ks);
        short8 bh = *(const short8*)(bh_p + ks);
        short8 bl = *(const short8*)(bl_p + ks);
        acc = __builtin_amdgcn_mfma_f32_32x32x16_bf16(ah, bh, acc, 0, 0, 0);
        acc = __builtin_amdgcn_mfma_f32_32x32x16_bf16(ah, bl, acc, 0, 0, 0);
        acc = __builtin_amdgcn_mfma_f32_32x32x16_bf16(al, bh, acc, 0, 0, 0);
    }

    const float C2L = 2.8853900817779268f;  // 2*log2(e)
    float* ob = op + (size_t)m0 * HH + nt * 32;
    #pragma unroll
    for (int r = 0; r < 16; r++) {
        const int rb = (r & 3) + 8 * (r >> 2) + 4 * kg;
        ob[(size_t)rb * HH + row] = exp2_fast(acc[r] * C2L);
    }
}

// ---------------------------------------------------------------------------
// Kernel 3: P = exp(-2 * sum_h w_v[h]/(eq*ek+1)) as bf16 hi/lo + rsp partials.
// 4 h-terms share ONE rcp via common denominator; u clamped at 3e7.
// NOTE: launched 3x this round (idempotent) as a timing diagnostic —
// total_delta / 2 = T_scores.
// ---------------------------------------------------------------------------
__global__ __launch_bounds__(256) void scores_kernel(
    const float* __restrict__ eq, const float* __restrict__ ek,
    const float* __restrict__ wv, ushort* __restrict__ Phi,
    ushort* __restrict__ Plo, float* __restrict__ rsp)
{
    __shared__ float eqs[64][68];
    __shared__ float eks[64][68];

    const int tid = threadIdx.x;
    const int b  = blockIdx.z;
    const int q0 = blockIdx.y * 64;
    const int k0 = blockIdx.x * 64;

    const float* eqb = eq + ((size_t)b * QS  + q0) * HH;
    const float* ekb = ek + ((size_t)b * KSZ + k0) * HH;

    const int tk = tid & 15;
    const int tq = tid >> 4;

    float acc[4][4] = {};

    for (int hc = 0; hc < HH; hc += 64) {
        __syncthreads();
        #pragma unroll
        for (int i = 0; i < 4; i++) {
            int f = tid + i * 256;
            int row = f >> 4, c4 = f & 15;
            *(float4*)&eqs[row][c4 * 4] =
                *(const float4*)&eqb[(size_t)row * HH + hc + c4 * 4];
            *(float4*)&eks[row][c4 * 4] =
                *(const float4*)&ekb[(size_t)row * HH + hc + c4 * 4];
        }
        __syncthreads();

        for (int h0 = 0; h0 < 64; h0 += 4) {
            float4 wv4 = *(const float4*)&wv[hc + h0];   // uniform -> s_load
            float4 eq4[4], ek4[4];
            #pragma unroll
            for (int j = 0; j < 4; j++) {
                eq4[j] = *(const float4*)&eqs[tq + 16 * j][h0];
                ek4[j] = *(const float4*)&eks[tk + 16 * j][h0];
            }
            #pragma unroll
            for (int jq = 0; jq < 4; jq++) {
                #pragma unroll
                for (int jk = 0; jk < 4; jk++) {
                    float u0 = fminf(fmaf(eq4[jq].x, ek4[jk].x, 1.0f), 3e7f);
                    float u1 = fminf(fmaf(eq4[jq].y, ek4[jk].y, 1.0f), 3e7f);
                    float u2 = fminf(fmaf(eq4[jq].z, ek4[jk].z, 1.0f), 3e7f);
                    float u3 = fminf(fmaf(eq4[jq].w, ek4[jk].w, 1.0f), 3e7f);
                    float p01 = u0 * u1, p23 = u2 * u3;
                    float n01 = fmaf(wv4.x, u1, wv4.y * u0);
                    float n23 = fmaf(wv4.z, u3, wv4.w * u2);
                    float N = fmaf(n01, p23, n23 * p01);
                    acc[jq][jk] = fmaf(N, rcp_fast(p01 * p23), acc[jq][jk]);
                }
            }
        }
    }

    const float CN = -2.8853900817779268f;  // -2*log2(e)
    ushort* ph = Phi + ((size_t)b * QS + q0) * KSZ + k0;
    ushort* pl = Plo + ((size_t)b * QS + q0) * KSZ + k0;
    #pragma unroll
    for (int jq = 0; jq < 4; jq++) {
        float rowp = 0.f;
        #pragma unroll
        for (int jk = 0; jk < 4; jk++) {
            float pv_ = exp2_fast(acc[jq][jk] * CN);
            ushort hh, ll; split1(pv_, hh, ll);
            size_t o = (size_t)(tq + 16 * jq) * KSZ + tk + 16 * jk;
            ph[o] = hh; pl[o] = ll;
            rowp += pv_;
        }
        #pragma unroll
        for (int m = 8; m; m >>= 1) rowp += __shfl_xor(rowp, m);
        if ((tid & 15) == 0)
            rsp[((size_t)b * QS + q0 + tq + 16 * jq) * 16 + blockIdx.x] = rowp;
    }
}

// ---------------------------------------------------------------------------
// Kernel 4: out = P @ V / rowsum via MFMA (PhVh + PhVl + PlVh). 512 blocks:
// 4 waves = 2 nt x 2 K-halves (merged via LDS), dual accumulator chains.
// ---------------------------------------------------------------------------
__global__ __launch_bounds__(256) void pv_mfma_kernel(
    const ushort* __restrict__ Phi, const ushort* __restrict__ Plo,
    const ushort* __restrict__ vhi, const ushort* __restrict__ vlo,
    const float* __restrict__ rsp, float* __restrict__ outp)
{
    __shared__ float invs[32];
    __shared__ float accs[2][32][33];

    const int id  = blockIdx.x;         // 512 blocks
    const int x   = id & 7;             // ~XCD
    const int j   = id >> 3;            // 0..63
    const int bm  = x * 8 + (j >> 3);   // 0..63
    const int ntp = j & 7;              // nt pair
    const int b   = bm >> 4, mt = bm & 15;

    const int tid = threadIdx.x, w = tid >> 6, lane = tid & 63;
    const int row = lane & 31, kg = lane >> 5;

    if (tid < 32) {
        const float* rp = rsp + ((size_t)b * QS + mt * 32 + tid) * 16;
        float s = 0.f;
        #pragma unroll
        for (int i = 0; i < 16; i++) s += rp[i];
        invs[tid] = rcp_fast(s);
    }

    const int nt  = ntp * 2 + (w >> 1);
    const int kh0 = (w & 1) * (KSZ / 2);

    const ushort* pah = Phi + ((size_t)b * QS  + mt * 32 + row) * KSZ + kh0 + kg * 8;
    const ushort* pal = Plo + ((size_t)b * QS  + mt * 32 + row) * KSZ + kh0 + kg * 8;
    const ushort* bhp = vhi + ((size_t)b * DVV + nt * 32 + row) * KSZ + kh0 + kg * 8;
    const ushort* blp = vlo + ((size_t)b * DVV + nt * 32 + row) * KSZ + kh0 + kg * 8;

    f32x16 acc0, acc1;
    #pragma unroll
    for (int i = 0; i < 16; i++) { acc0[i] = 0.f; acc1[i] = 0.f; }

    #pragma unroll 4
    for (int kb = 0; kb < KSZ / 2; kb += 32) {
        short8 a0h = *(const short8*)(pah + kb);
        short8 a0l = *(const short8*)(pal + kb);
        short8 v0h = *(const short8*)(bhp + kb);
        short8 v0l = *(const short8*)(blp + kb);
        short8 a1h = *(const short8*)(pah + kb + 16);
        short8 a1l = *(const short8*)(pal + kb + 16);
        short8 v1h = *(const short8*)(bhp + kb + 16);
        short8 v1l = *(const short8*)(blp + kb + 16);
        acc0 = __builtin_amdgcn_mfma_f32_32x32x16_bf16(a0h, v0h, acc0, 0, 0, 0);
        acc1 = __builtin_amdgcn_mfma_f32_32x32x16_bf16(a1h, v1h, acc1, 0, 0, 0);
        acc0 = __builtin_amdgcn_mfma_f32_32x32x16_bf16(a0h, v0l, acc0, 0, 0, 0);
        acc1 = __builtin_amdgcn_mfma_f32_32x32x16_bf16(a1h, v1l, acc1, 0, 0, 0);
        acc0 = __builtin_amdgcn_mfma_f32_32x32x16_bf16(a0l, v0h, acc0, 0, 0, 0);
        acc1 = __builtin_amdgcn_mfma_f32_32x32x16_bf16(a1l, v1h, acc1, 0, 0, 0);
    }
    #pragma unroll
    for (int i = 0; i < 16; i++) acc0[i] += acc1[i];

    // C/D layout: col = lane&31, row = (r&3) + 8*(r>>2) + 4*kg
    if (w & 1) {
        #pragma unroll
        for (int r = 0; r < 16; r++)
            accs[w >> 1][(r & 3) + 8 * (r >> 2) + 4 * kg][row] = acc0[r];
    }
    __syncthreads();
    if (!(w & 1)) {
        float* ob = outp + ((size_t)b * QS + mt * 32) * DVV + nt * 32;
        #pragma unroll
        for (int r = 0; r < 16; r++) {
            const int rb = (r & 3) + 8 * (r >> 2) + 4 * kg;
            float v = acc0[r] + accs[w >> 1][rb][row];
            ob[(size_t)rb * DVV + row] = v * invs[rb];
        }
    }
}

// ---------------------------------------------------------------------------
extern "C" void kernel_launch(void* const* d_in, const int* in_sizes, int n_in,
                              void* d_out, int out_size, void* d_ws, size_t ws_size,
                              hipStream_t stream)
{
    const float* queries = (const float*)d_in[0];
    const float* keys    = (const float*)d_in[1];
    const float* values  = (const float*)d_in[2];
    const float* Wq      = (const float*)d_in[3];
    const float* Wk      = (const float*)d_in[4];
    const float* wv      = (const float*)d_in[5];
    float* out = (float*)d_out;

    // float region
    float*  eq  = (float*)d_ws;
    float*  ek  = eq + (size_t)BB * QS * HH;
    float*  rsp = ek + (size_t)BB * KSZ * HH;
    // ushort region
    ushort* Phi = (ushort*)(rsp + (size_t)BB * QS * 16);
    ushort* Plo = Phi + (size_t)BB * QS * KSZ;
    ushort* vhi = Plo + (size_t)BB * QS * KSZ;
    ushort* vlo = vhi + (size_t)BB * KSZ * DVV;
    ushort* qh  = vlo + (size_t)BB * KSZ * DVV;
    ushort* ql  = qh  + (size_t)BB * QS * DD;
    ushort* kh  = ql  + (size_t)BB * QS * DD;
    ushort* kl  = kh  + (size_t)BB * KSZ * DD;
    ushort* wqh = kl  + (size_t)BB * KSZ * DD;
    ushort* wql = wqh + (size_t)HH * DD;
    ushort* wkh = wql + (size_t)HH * DD;
    ushort* wkl = wkh + (size_t)HH * DD;

    split_kernel<<<dim3(NSQ + NSK + NWT), 256, 0, stream>>>(
        queries, keys, Wq, Wk, qh, ql, kh, kl, wqh, wql, wkh, wkl);

    projvt_kernel<<<dim3(NPJ + NVT), 256, 0, stream>>>(
        qh, ql, kh, kl, wqh, wql, wkh, wkl, values, eq, ek, vhi, vlo);

    // DIAGNOSTIC: scores launched 3x (idempotent). (total - 161.2)/2 = T_scores.
    scores_kernel<<<dim3(KSZ / 64, QS / 64, BB), 256, 0, stream>>>(
        eq, ek, wv, Phi, Plo, rsp);
    scores_kernel<<<dim3(KSZ / 64, QS / 64, BB), 256, 0, stream>>>(
        eq, ek, wv, Phi, Plo, rsp);
    scores_kernel<<<dim3(KSZ / 64, QS / 64, BB), 256, 0, stream>>>(
        eq, ek, wv, Phi, Plo, rsp);

    pv_mfma_kernel<<<dim3(512), 256, 0, stream>>>(Phi, Plo, vhi, vlo, rsp, out);
}

// Round 11
// 154.303 us; speedup vs baseline: 1.4833x; 1.4833x over previous
//
#include <hip/hip_runtime.h>

#define BB   4
#define QS   512
#define KSZ  1024
#define DD   512
#define HH   128
#define DVV  512

typedef unsigned int uint;
typedef unsigned short ushort;
typedef unsigned long long ull;
typedef __attribute__((ext_vector_type(8)))  short short8;   // 8 bf16 (4 VGPRs)
typedef __attribute__((ext_vector_type(16))) float f32x16;   // MFMA 32x32 acc

__device__ __forceinline__ float rcp_fast(float x)  { return __builtin_amdgcn_rcpf(x); }
__device__ __forceinline__ float exp2_fast(float x) { return __builtin_amdgcn_exp2f(x); }

// split fp32 -> bf16 hi (truncate) + bf16 lo (residual); ~2^-17 rel combined
__device__ __forceinline__ void split1(float v, ushort& h, ushort& l) {
    uint u = __float_as_uint(v);
    h = (ushort)(u >> 16);
    float r = v - __uint_as_float(u & 0xffff0000u);
    l = (ushort)(__float_as_uint(r) >> 16);
}

// split_kernel grid segments (q/k/W only; V^T lives in projvt_kernel)
#define NSQ  (BB * QS * DD / 4 / 256)     // 1024
#define NSK  (BB * KSZ * DD / 4 / 256)    // 2048
#define NWT  128                          // 64 per W
#define NPJ  192                          // proj blocks (768 waves)
#define NVT  (BB * (KSZ / 32) * (DVV / 32))  // 2048 V-transpose blocks

// ---------------------------------------------------------------------------
// Kernel 1: bf16 pre-split of q, k (element-wise) and W_q/W_k (transpose to
// [h][d]). Pure memory-bound, ~25 MB.
// ---------------------------------------------------------------------------
__global__ __launch_bounds__(256) void split_kernel(
    const float* __restrict__ q, const float* __restrict__ k,
    const float* __restrict__ Wq, const float* __restrict__ Wk,
    ushort* __restrict__ qh, ushort* __restrict__ ql,
    ushort* __restrict__ kh, ushort* __restrict__ kl,
    ushort* __restrict__ wqh, ushort* __restrict__ wql,
    ushort* __restrict__ wkh, ushort* __restrict__ wkl)
{
    const int id  = blockIdx.x;
    const int tid = threadIdx.x;

    if (id < NSQ + NSK) {
        const float* src; ushort* dh; ushort* dl; size_t i;
        if (id < NSQ) { src = q; dh = qh; dl = ql; i = (size_t)id * 256 + tid; }
        else          { src = k; dh = kh; dl = kl; i = (size_t)(id - NSQ) * 256 + tid; }
        float4 v = ((const float4*)src)[i];
        ushort h0,h1,h2,h3,l0,l1,l2,l3;
        split1(v.x,h0,l0); split1(v.y,h1,l1); split1(v.z,h2,l2); split1(v.w,h3,l3);
        *(ushort4*)&dh[i * 4] = make_ushort4(h0,h1,h2,h3);
        *(ushort4*)&dl[i * 4] = make_ushort4(l0,l1,l2,l3);
        return;
    }
    // ---- W transpose + split: [512][128] -> [128][512] hi/lo ----
    __shared__ float Ts[32][33];
    int t = id - (NSQ + NSK);
    const float* W; ushort* dh; ushort* dl;
    if (t < 64) { W = Wq; dh = wqh; dl = wql; }
    else        { W = Wk; dh = wkh; dl = wkl; t -= 64; }
    const int d0 = (t >> 2) * 32, h0 = (t & 3) * 32;
    {
        const int dd = tid >> 3, c4 = (tid & 7) * 4;
        float4 v = *(const float4*)&W[(size_t)(d0 + dd) * HH + h0 + c4];
        Ts[dd][c4 + 0] = v.x; Ts[dd][c4 + 1] = v.y;
        Ts[dd][c4 + 2] = v.z; Ts[dd][c4 + 3] = v.w;
    }
    __syncthreads();
    {
        const int hh = tid >> 3, d4 = (tid & 7) * 4;
        ushort h[4], l[4];
        #pragma unroll
        for (int i = 0; i < 4; i++) split1(Ts[d4 + i][hh], h[i], l[i]);
        size_t o = (size_t)(h0 + hh) * DD + d0 + d4;
        *(ushort4*)&dh[o] = make_ushort4(h[0], h[1], h[2], h[3]);
        *(ushort4*)&dl[o] = make_ushort4(l[0], l[1], l[2], l[3]);
    }
}

// ---------------------------------------------------------------------------
// Kernel 2 (fused): blocks [0,NPJ) = projection via MFMA (pre-split bf16
// operands, b128 loads, 3 MFMAs/k16) + exp(2x). Blocks [NPJ,+NVT) = V
// transpose+split (memory-bound backfill behind proj's 192-block tail).
// ---------------------------------------------------------------------------
__global__ __launch_bounds__(256) void projvt_kernel(
    const ushort* __restrict__ qh, const ushort* __restrict__ ql,
    const ushort* __restrict__ kh, const ushort* __restrict__ kl,
    const ushort* __restrict__ wqh, const ushort* __restrict__ wql,
    const ushort* __restrict__ wkh, const ushort* __restrict__ wkl,
    const float* __restrict__ val,
    float* __restrict__ eq, float* __restrict__ ek,
    ushort* __restrict__ vhi, ushort* __restrict__ vlo)
{
    const int id  = blockIdx.x;
    const int tid = threadIdx.x;

    if (id >= NPJ) {
        __shared__ float Ts[32][33];
        const int t   = id - NPJ;
        const int b   = t >> 9;
        const int rem = t & 511;
        const int k0  = (rem >> 4) * 32;
        const int n0  = (rem & 15) * 32;
        {
            const int kk = tid >> 3, n4 = (tid & 7) * 4;
            float4 v = *(const float4*)&val[((size_t)b * KSZ + k0 + kk) * DVV + n0 + n4];
            Ts[kk][n4 + 0] = v.x; Ts[kk][n4 + 1] = v.y;
            Ts[kk][n4 + 2] = v.z; Ts[kk][n4 + 3] = v.w;
        }
        __syncthreads();
        {
            const int nn = tid >> 3, k4 = (tid & 7) * 4;
            ushort h[4], l[4];
            #pragma unroll
            for (int i = 0; i < 4; i++) split1(Ts[k4 + i][nn], h[i], l[i]);
            size_t o = ((size_t)b * DVV + n0 + nn) * KSZ + k0 + k4;
            *(ushort4*)&vhi[o] = make_ushort4(h[0], h[1], h[2], h[3]);
            *(ushort4*)&vlo[o] = make_ushort4(l[0], l[1], l[2], l[3]);
        }
        return;
    }

    // ---- projection: eq/ek[m][h] = exp2(C2L * sum_d A[m][d]*W[d][h]) ----
    const int w = tid >> 6, lane = tid & 63;
    const int row = lane & 31, kg = lane >> 5;
    const int gw = id * 4 + w;                  // 0..767

    const ushort *pa_h, *pa_l, *pb_h, *pb_l; float* op; int m0, nt;
    if (gw < 256) {
        m0 = (gw >> 2) * 32; nt = gw & 3;
        pa_h = qh; pa_l = ql; pb_h = wqh; pb_l = wql; op = eq;
    } else {
        const int g = gw - 256;
        m0 = (g >> 2) * 32; nt = g & 3;
        pa_h = kh; pa_l = kl; pb_h = wkh; pb_l = wkl; op = ek;
    }

    const ushort* ah_p = pa_h + (size_t)(m0 + row) * DD + kg * 8;
    const ushort* al_p = pa_l + (size_t)(m0 + row) * DD + kg * 8;
    const ushort* bh_p = pb_h + (size_t)(nt * 32 + row) * DD + kg * 8;
    const ushort* bl_p = pb_l + (size_t)(nt * 32 + row) * DD + kg * 8;

    f32x16 acc;
    #pragma unroll
    for (int i = 0; i < 16; i++) acc[i] = 0.f;

    #pragma unroll 8
    for (int ks = 0; ks < DD; ks += 16) {
        short8 ah = *(const short8*)(ah_p + ks);
        short8 al = *(const short8*)(al_p + ks);
        short8 bh = *(const short8*)(bh_p + ks);
        short8 bl = *(const short8*)(bl_p + ks);
        acc = __builtin_amdgcn_mfma_f32_32x32x16_bf16(ah, bh, acc, 0, 0, 0);
        acc = __builtin_amdgcn_mfma_f32_32x32x16_bf16(ah, bl, acc, 0, 0, 0);
        acc = __builtin_amdgcn_mfma_f32_32x32x16_bf16(al, bh, acc, 0, 0, 0);
    }

    const float C2L = 2.8853900817779268f;  // 2*log2(e)
    float* ob = op + (size_t)m0 * HH + nt * 32;
    #pragma unroll
    for (int r = 0; r < 16; r++) {
        const int rb = (r & 3) + 8 * (r >> 2) + 4 * kg;
        ob[(size_t)rb * HH + row] = exp2_fast(acc[r] * C2L);
    }
}

// ---------------------------------------------------------------------------
// Kernel 3: P = exp(-2 * sum_h w_v[h]/(eq*ek+1)) as bf16 hi/lo + rsp partials
// (8 per row, k-tiles of 128). Tile 64q x 128k, thread tile 4x8: 12 b128 LDS
// reads feed 128 (elem,h) pairs (2.7x less LDS than 4x4). Batched rcp.
// ---------------------------------------------------------------------------
__global__ __launch_bounds__(256) void scores_kernel(
    const float* __restrict__ eq, const float* __restrict__ ek,
    const float* __restrict__ wv, ushort* __restrict__ Phi,
    ushort* __restrict__ Plo, float* __restrict__ rsp)
{
    __shared__ float eqs[64][68];
    __shared__ float eks[128][68];

    const int tid = threadIdx.x;
    const int b  = blockIdx.z;
    const int q0 = blockIdx.y * 64;
    const int k0 = blockIdx.x * 128;

    const float* eqb = eq + ((size_t)b * QS  + q0) * HH;
    const float* ekb = ek + ((size_t)b * KSZ + k0) * HH;

    const int tk = tid & 15;
    const int tq = tid >> 4;

    float acc[4][8] = {};

    for (int hc = 0; hc < HH; hc += 64) {
        __syncthreads();
        #pragma unroll
        for (int i = 0; i < 4; i++) {          // 64 x 64 eq tile
            int f = tid + i * 256;
            int row = f >> 4, c4 = f & 15;
            *(float4*)&eqs[row][c4 * 4] =
                *(const float4*)&eqb[(size_t)row * HH + hc + c4 * 4];
        }
        #pragma unroll
        for (int i = 0; i < 8; i++) {          // 128 x 64 ek tile
            int f = tid + i * 256;
            int row = f >> 4, c4 = f & 15;
            *(float4*)&eks[row][c4 * 4] =
                *(const float4*)&ekb[(size_t)row * HH + hc + c4 * 4];
        }
        __syncthreads();

        for (int h0 = 0; h0 < 64; h0 += 4) {
            float4 wv4 = *(const float4*)&wv[hc + h0];   // uniform -> s_load
            float4 eq4[4], ek8[8];
            #pragma unroll
            for (int j = 0; j < 4; j++) eq4[j] = *(const float4*)&eqs[tq + 16 * j][h0];
            #pragma unroll
            for (int j = 0; j < 8; j++) ek8[j] = *(const float4*)&eks[tk + 16 * j][h0];
            #pragma unroll
            for (int jq = 0; jq < 4; jq++) {
                #pragma unroll
                for (int jk = 0; jk < 8; jk++) {
                    float u0 = fminf(fmaf(eq4[jq].x, ek8[jk].x, 1.0f), 3e7f);
                    float u1 = fminf(fmaf(eq4[jq].y, ek8[jk].y, 1.0f), 3e7f);
                    float u2 = fminf(fmaf(eq4[jq].z, ek8[jk].z, 1.0f), 3e7f);
                    float u3 = fminf(fmaf(eq4[jq].w, ek8[jk].w, 1.0f), 3e7f);
                    float p01 = u0 * u1, p23 = u2 * u3;
                    float n01 = fmaf(wv4.x, u1, wv4.y * u0);
                    float n23 = fmaf(wv4.z, u3, wv4.w * u2);
                    float N = fmaf(n01, p23, n23 * p01);
                    acc[jq][jk] = fmaf(N, rcp_fast(p01 * p23), acc[jq][jk]);
                }
            }
        }
    }

    const float CN = -2.8853900817779268f;  // -2*log2(e)
    ushort* ph = Phi + ((size_t)b * QS + q0) * KSZ + k0;
    ushort* pl = Plo + ((size_t)b * QS + q0) * KSZ + k0;
    #pragma unroll
    for (int jq = 0; jq < 4; jq++) {
        float rowp = 0.f;
        #pragma unroll
        for (int jk = 0; jk < 8; jk++) {
            float pv_ = exp2_fast(acc[jq][jk] * CN);
            ushort hh, ll; split1(pv_, hh, ll);
            size_t o = (size_t)(tq + 16 * jq) * KSZ + tk + 16 * jk;
            ph[o] = hh; pl[o] = ll;
            rowp += pv_;
        }
        #pragma unroll
        for (int m = 8; m; m >>= 1) rowp += __shfl_xor(rowp, m);
        if ((tid & 15) == 0)
            rsp[((size_t)b * QS + q0 + tq + 16 * jq) * 8 + blockIdx.x] = rowp;
    }
}

// ---------------------------------------------------------------------------
// Kernel 4: out = P @ V / rowsum via MFMA, LDS-STAGED: coalesced 128B-segment
// global reads -> LDS (stride 68 ushort, b64 accesses: 8B-aligned, 2-way
// banks = free) -> fragment reads -> 3 MFMAs/k16. Block = 64m x 64n, 4 waves
// = 2x2 of 32x32 (full K each, no merge). 16 K-chunks of 64, register
// prefetch of chunk c+1 before compute of c. 256 blocks, XCD swizzle.
// ---------------------------------------------------------------------------
__global__ __launch_bounds__(256) void pv_mfma_kernel(
    const ushort* __restrict__ Phi, const ushort* __restrict__ Plo,
    const ushort* __restrict__ vhi, const ushort* __restrict__ vlo,
    const float* __restrict__ rsp, float* __restrict__ outp)
{
    __shared__ ushort PhS[64][68];
    __shared__ ushort PlS[64][68];
    __shared__ ushort VhS[64][68];
    __shared__ ushort VlS[64][68];
    __shared__ float invs[64];

    const int id  = blockIdx.x;         // 256 blocks
    const int x   = id & 7;             // ~XCD
    const int g   = id >> 3;            // 0..31
    const int bmg = x * 4 + (g >> 3);   // 0..31
    const int b   = bmg >> 3, mt = bmg & 7;   // 64-row m-tile
    const int ntB = g & 7;                    // 64-col n-tile

    const int tid = threadIdx.x, w = tid >> 6, lane = tid & 63;
    const int col = lane & 31, kg = lane >> 5;

    if (tid < 64) {
        const float* rp = rsp + ((size_t)b * QS + mt * 64 + tid) * 8;
        float s = 0.f;
        #pragma unroll
        for (int i = 0; i < 8; i++) s += rp[i];
        invs[tid] = rcp_fast(s);
    }

    const int wm = (w & 1) * 32, wn = (w >> 1) * 32;

    // staging: thread -> row sr (0..63), 32B at short-offset cc
    const int sr = tid >> 2, cc = (tid & 3) * 16;
    const ushort* gPh = Phi + ((size_t)b * QS  + mt * 64 + sr) * KSZ + cc;
    const ushort* gPl = Plo + ((size_t)b * QS  + mt * 64 + sr) * KSZ + cc;
    const ushort* gVh = vhi + ((size_t)b * DVV + ntB * 64 + sr) * KSZ + cc;
    const ushort* gVl = vlo + ((size_t)b * DVV + ntB * 64 + sr) * KSZ + cc;

    f32x16 acc;
    #pragma unroll
    for (int i = 0; i < 16; i++) acc[i] = 0.f;

    uint4 rph0, rph1, rpl0, rpl1, rvh0, rvh1, rvl0, rvl1;
#define LOADC(kc) \
    rph0 = *(const uint4*)(gPh + (kc)); rph1 = *(const uint4*)(gPh + (kc) + 8); \
    rpl0 = *(const uint4*)(gPl + (kc)); rpl1 = *(const uint4*)(gPl + (kc) + 8); \
    rvh0 = *(const uint4*)(gVh + (kc)); rvh1 = *(const uint4*)(gVh + (kc) + 8); \
    rvl0 = *(const uint4*)(gVl + (kc)); rvl1 = *(const uint4*)(gVl + (kc) + 8);
#define STOREC() { \
    ull* dPh = (ull*)&PhS[sr][cc]; ull* dPl = (ull*)&PlS[sr][cc]; \
    ull* dVh = (ull*)&VhS[sr][cc]; ull* dVl = (ull*)&VlS[sr][cc]; \
    dPh[0] = ((ull*)&rph0)[0]; dPh[1] = ((ull*)&rph0)[1]; \
    dPh[2] = ((ull*)&rph1)[0]; dPh[3] = ((ull*)&rph1)[1]; \
    dPl[0] = ((ull*)&rpl0)[0]; dPl[1] = ((ull*)&rpl0)[1]; \
    dPl[2] = ((ull*)&rpl1)[0]; dPl[3] = ((ull*)&rpl1)[1]; \
    dVh[0] = ((ull*)&rvh0)[0]; dVh[1] = ((ull*)&rvh0)[1]; \
    dVh[2] = ((ull*)&rvh1)[0]; dVh[3] = ((ull*)&rvh1)[1]; \
    dVl[0] = ((ull*)&rvl0)[0]; dVl[1] = ((ull*)&rvl0)[1]; \
    dVl[2] = ((ull*)&rvl1)[0]; dVl[3] = ((ull*)&rvl1)[1]; }

    LOADC(0);
    STOREC();
    __syncthreads();

    for (int c = 0; c < 16; c++) {
        if (c < 15) { LOADC((c + 1) * 64); }
        #pragma unroll
        for (int kk = 0; kk < 4; kk++) {
            const int off = kk * 16 + kg * 8;
            short8 ah, al, vh, vl;
            { const ull* p = (const ull*)&PhS[wm + col][off];
              ((ull*)&ah)[0] = p[0]; ((ull*)&ah)[1] = p[1]; }
            { const ull* p = (const ull*)&PlS[wm + col][off];
              ((ull*)&al)[0] = p[0]; ((ull*)&al)[1] = p[1]; }
            { const ull* p = (const ull*)&VhS[wn + col][off];
              ((ull*)&vh)[0] = p[0]; ((ull*)&vh)[1] = p[1]; }
            { const ull* p = (const ull*)&VlS[wn + col][off];
              ((ull*)&vl)[0] = p[0]; ((ull*)&vl)[1] = p[1]; }
            acc = __builtin_amdgcn_mfma_f32_32x32x16_bf16(ah, vh, acc, 0, 0, 0);
            acc = __builtin_amdgcn_mfma_f32_32x32x16_bf16(ah, vl, acc, 0, 0, 0);
            acc = __builtin_amdgcn_mfma_f32_32x32x16_bf16(al, vh, acc, 0, 0, 0);
        }
        __syncthreads();                 // all waves done reading this chunk
        if (c < 15) { STOREC(); __syncthreads(); }
    }

    // C/D layout: col = lane&31, row = (r&3) + 8*(r>>2) + 4*kg
    float* ob = outp + ((size_t)b * QS + mt * 64 + wm) * DVV + ntB * 64 + wn;
    #pragma unroll
    for (int r = 0; r < 16; r++) {
        const int rb = (r & 3) + 8 * (r >> 2) + 4 * kg;
        ob[(size_t)rb * DVV + col] = acc[r] * invs[wm + rb];
    }
#undef LOADC
#undef STOREC
}

// ---------------------------------------------------------------------------
extern "C" void kernel_launch(void* const* d_in, const int* in_sizes, int n_in,
                              void* d_out, int out_size, void* d_ws, size_t ws_size,
                              hipStream_t stream)
{
    const float* queries = (const float*)d_in[0];
    const float* keys    = (const float*)d_in[1];
    const float* values  = (const float*)d_in[2];
    const float* Wq      = (const float*)d_in[3];
    const float* Wk      = (const float*)d_in[4];
    const float* wv      = (const float*)d_in[5];
    float* out = (float*)d_out;

    // float region
    float*  eq  = (float*)d_ws;                       // 262144 floats
    float*  ek  = eq + (size_t)BB * QS * HH;          // 524288
    float*  rsp = ek + (size_t)BB * KSZ * HH;         // 16384 (8 per row now)
    // ushort region
    ushort* Phi = (ushort*)(rsp + (size_t)BB * QS * 8);
    ushort* Plo = Phi + (size_t)BB * QS * KSZ;
    ushort* vhi = Plo + (size_t)BB * QS * KSZ;
    ushort* vlo = vhi + (size_t)BB * KSZ * DVV;
    ushort* qh  = vlo + (size_t)BB * KSZ * DVV;
    ushort* ql  = qh  + (size_t)BB * QS * DD;
    ushort* kh  = ql  + (size_t)BB * QS * DD;
    ushort* kl  = kh  + (size_t)BB * KSZ * DD;
    ushort* wqh = kl  + (size_t)BB * KSZ * DD;
    ushort* wql = wqh + (size_t)HH * DD;
    ushort* wkh = wql + (size_t)HH * DD;
    ushort* wkl = wkh + (size_t)HH * DD;

    split_kernel<<<dim3(NSQ + NSK + NWT), 256, 0, stream>>>(
        queries, keys, Wq, Wk, qh, ql, kh, kl, wqh, wql, wkh, wkl);

    projvt_kernel<<<dim3(NPJ + NVT), 256, 0, stream>>>(
        qh, ql, kh, kl, wqh, wql, wkh, wkl, values, eq, ek, vhi, vlo);

    scores_kernel<<<dim3(KSZ / 128, QS / 64, BB), 256, 0, stream>>>(
        eq, ek, wv, Phi, Plo, rsp);

    pv_mfma_kernel<<<dim3(256), 256, 0, stream>>>(Phi, Plo, vhi, vlo, rsp, out);
}

// Round 12
// 147.775 us; speedup vs baseline: 1.5489x; 1.0442x over previous
//
#include <hip/hip_runtime.h>

#define BB   4
#define QS   512
#define KSZ  1024
#define DD   512
#define HH   128
#define DVV  512

typedef unsigned int uint;
typedef unsigned short ushort;
typedef unsigned long long ull;
typedef __attribute__((ext_vector_type(8)))  short short8;   // 8 bf16 (4 VGPRs)
typedef __attribute__((ext_vector_type(16))) float f32x16;   // MFMA 32x32 acc

__device__ __forceinline__ float rcp_fast(float x)  { return __builtin_amdgcn_rcpf(x); }
__device__ __forceinline__ float exp2_fast(float x) { return __builtin_amdgcn_exp2f(x); }

// split fp32 -> bf16 hi (truncate) + bf16 lo (residual); ~2^-17 rel combined
__device__ __forceinline__ void split1(float v, ushort& h, ushort& l) {
    uint u = __float_as_uint(v);
    h = (ushort)(u >> 16);
    float r = v - __uint_as_float(u & 0xffff0000u);
    l = (ushort)(__float_as_uint(r) >> 16);
}

// split_kernel grid segments (q/k/W only; V^T lives in projvt_kernel)
#define NSQ  (BB * QS * DD / 4 / 256)     // 1024
#define NSK  (BB * KSZ * DD / 4 / 256)    // 2048
#define NWT  128                          // 64 per W
#define NPJ  192                          // proj blocks (768 waves)
#define NVT  (BB * (KSZ / 32) * (DVV / 32))  // 2048 V-transpose blocks

// ---------------------------------------------------------------------------
// Kernel 1: bf16 pre-split of q, k (element-wise) and W_q/W_k (transpose to
// [h][d]). Pure memory-bound, ~25 MB.
// ---------------------------------------------------------------------------
__global__ __launch_bounds__(256) void split_kernel(
    const float* __restrict__ q, const float* __restrict__ k,
    const float* __restrict__ Wq, const float* __restrict__ Wk,
    ushort* __restrict__ qh, ushort* __restrict__ ql,
    ushort* __restrict__ kh, ushort* __restrict__ kl,
    ushort* __restrict__ wqh, ushort* __restrict__ wql,
    ushort* __restrict__ wkh, ushort* __restrict__ wkl)
{
    const int id  = blockIdx.x;
    const int tid = threadIdx.x;

    if (id < NSQ + NSK) {
        const float* src; ushort* dh; ushort* dl; size_t i;
        if (id < NSQ) { src = q; dh = qh; dl = ql; i = (size_t)id * 256 + tid; }
        else          { src = k; dh = kh; dl = kl; i = (size_t)(id - NSQ) * 256 + tid; }
        float4 v = ((const float4*)src)[i];
        ushort h0,h1,h2,h3,l0,l1,l2,l3;
        split1(v.x,h0,l0); split1(v.y,h1,l1); split1(v.z,h2,l2); split1(v.w,h3,l3);
        *(ushort4*)&dh[i * 4] = make_ushort4(h0,h1,h2,h3);
        *(ushort4*)&dl[i * 4] = make_ushort4(l0,l1,l2,l3);
        return;
    }
    // ---- W transpose + split: [512][128] -> [128][512] hi/lo ----
    __shared__ float Ts[32][33];
    int t = id - (NSQ + NSK);
    const float* W; ushort* dh; ushort* dl;
    if (t < 64) { W = Wq; dh = wqh; dl = wql; }
    else        { W = Wk; dh = wkh; dl = wkl; t -= 64; }
    const int d0 = (t >> 2) * 32, h0 = (t & 3) * 32;
    {
        const int dd = tid >> 3, c4 = (tid & 7) * 4;
        float4 v = *(const float4*)&W[(size_t)(d0 + dd) * HH + h0 + c4];
        Ts[dd][c4 + 0] = v.x; Ts[dd][c4 + 1] = v.y;
        Ts[dd][c4 + 2] = v.z; Ts[dd][c4 + 3] = v.w;
    }
    __syncthreads();
    {
        const int hh = tid >> 3, d4 = (tid & 7) * 4;
        ushort h[4], l[4];
        #pragma unroll
        for (int i = 0; i < 4; i++) split1(Ts[d4 + i][hh], h[i], l[i]);
        size_t o = (size_t)(h0 + hh) * DD + d0 + d4;
        *(ushort4*)&dh[o] = make_ushort4(h[0], h[1], h[2], h[3]);
        *(ushort4*)&dl[o] = make_ushort4(l[0], l[1], l[2], l[3]);
    }
}

// ---------------------------------------------------------------------------
// Kernel 2 (fused): blocks [0,NPJ) = projection via MFMA (pre-split bf16
// operands, b128 loads, 3 MFMAs/k16) + exp(2x). Blocks [NPJ,+NVT) = V
// transpose+split (memory-bound backfill behind proj's 192-block tail).
// ---------------------------------------------------------------------------
__global__ __launch_bounds__(256) void projvt_kernel(
    const ushort* __restrict__ qh, const ushort* __restrict__ ql,
    const ushort* __restrict__ kh, const ushort* __restrict__ kl,
    const ushort* __restrict__ wqh, const ushort* __restrict__ wql,
    const ushort* __restrict__ wkh, const ushort* __restrict__ wkl,
    const float* __restrict__ val,
    float* __restrict__ eq, float* __restrict__ ek,
    ushort* __restrict__ vhi, ushort* __restrict__ vlo)
{
    const int id  = blockIdx.x;
    const int tid = threadIdx.x;

    if (id >= NPJ) {
        __shared__ float Ts[32][33];
        const int t   = id - NPJ;
        const int b   = t >> 9;
        const int rem = t & 511;
        const int k0  = (rem >> 4) * 32;
        const int n0  = (rem & 15) * 32;
        {
            const int kk = tid >> 3, n4 = (tid & 7) * 4;
            float4 v = *(const float4*)&val[((size_t)b * KSZ + k0 + kk) * DVV + n0 + n4];
            Ts[kk][n4 + 0] = v.x; Ts[kk][n4 + 1] = v.y;
            Ts[kk][n4 + 2] = v.z; Ts[kk][n4 + 3] = v.w;
        }
        __syncthreads();
        {
            const int nn = tid >> 3, k4 = (tid & 7) * 4;
            ushort h[4], l[4];
            #pragma unroll
            for (int i = 0; i < 4; i++) split1(Ts[k4 + i][nn], h[i], l[i]);
            size_t o = ((size_t)b * DVV + n0 + nn) * KSZ + k0 + k4;
            *(ushort4*)&vhi[o] = make_ushort4(h[0], h[1], h[2], h[3]);
            *(ushort4*)&vlo[o] = make_ushort4(l[0], l[1], l[2], l[3]);
        }
        return;
    }

    // ---- projection: eq/ek[m][h] = exp2(C2L * sum_d A[m][d]*W[d][h]) ----
    const int w = tid >> 6, lane = tid & 63;
    const int row = lane & 31, kg = lane >> 5;
    const int gw = id * 4 + w;                  // 0..767

    const ushort *pa_h, *pa_l, *pb_h, *pb_l; float* op; int m0, nt;
    if (gw < 256) {
        m0 = (gw >> 2) * 32; nt = gw & 3;
        pa_h = qh; pa_l = ql; pb_h = wqh; pb_l = wql; op = eq;
    } else {
        const int g = gw - 256;
        m0 = (g >> 2) * 32; nt = g & 3;
        pa_h = kh; pa_l = kl; pb_h = wkh; pb_l = wkl; op = ek;
    }

    const ushort* ah_p = pa_h + (size_t)(m0 + row) * DD + kg * 8;
    const ushort* al_p = pa_l + (size_t)(m0 + row) * DD + kg * 8;
    const ushort* bh_p = pb_h + (size_t)(nt * 32 + row) * DD + kg * 8;
    const ushort* bl_p = pb_l + (size_t)(nt * 32 + row) * DD + kg * 8;

    f32x16 acc;
    #pragma unroll
    for (int i = 0; i < 16; i++) acc[i] = 0.f;

    #pragma unroll 8
    for (int ks = 0; ks < DD; ks += 16) {
        short8 ah = *(const short8*)(ah_p + ks);
        short8 al = *(const short8*)(al_p + ks);
        short8 bh = *(const short8*)(bh_p + ks);
        short8 bl = *(const short8*)(bl_p + ks);
        acc = __builtin_amdgcn_mfma_f32_32x32x16_bf16(ah, bh, acc, 0, 0, 0);
        acc = __builtin_amdgcn_mfma_f32_32x32x16_bf16(ah, bl, acc, 0, 0, 0);
        acc = __builtin_amdgcn_mfma_f32_32x32x16_bf16(al, bh, acc, 0, 0, 0);
    }

    const float C2L = 2.8853900817779268f;  // 2*log2(e)
    float* ob = op + (size_t)m0 * HH + nt * 32;
    #pragma unroll
    for (int r = 0; r < 16; r++) {
        const int rb = (r & 3) + 8 * (r >> 2) + 4 * kg;
        ob[(size_t)rb * HH + row] = exp2_fast(acc[r] * C2L);
    }
}

// ---------------------------------------------------------------------------
// Kernel 3: P = exp(-2 * sum_h w_v[h]/(eq*ek+1)) as bf16 hi/lo + rsp partials
// (8 per row, k-tiles of 128). Tile 64q x 128k, 512 THREADS (8 waves/block ->
// 2 waves/SIMD at 1 block/CU; R11's 256-thread version ran 1 wave/SIMD,
// VALUBusy 51%). Thread tile 4q x 4k, batched rcp (1 per 4 h-terms).
// ---------------------------------------------------------------------------
__global__ __launch_bounds__(512) void scores_kernel(
    const float* __restrict__ eq, const float* __restrict__ ek,
    const float* __restrict__ wv, ushort* __restrict__ Phi,
    ushort* __restrict__ Plo, float* __restrict__ rsp)
{
    __shared__ float eqs[64][68];
    __shared__ float eks[128][68];

    const int tid = threadIdx.x;
    const int b  = blockIdx.z;
    const int q0 = blockIdx.y * 64;
    const int k0 = blockIdx.x * 128;

    const float* eqb = eq + ((size_t)b * QS  + q0) * HH;
    const float* ekb = ek + ((size_t)b * KSZ + k0) * HH;

    const int tk = tid & 31;    // k rows tk + 32*jk
    const int tq = tid >> 5;    // q rows tq + 16*jq

    float acc[4][4] = {};

    for (int hc = 0; hc < HH; hc += 64) {
        __syncthreads();
        #pragma unroll
        for (int i = 0; i < 2; i++) {          // 64 x 64 eq tile (1024 f4)
            int f = tid + i * 512;
            int row = f >> 4, c4 = f & 15;
            *(float4*)&eqs[row][c4 * 4] =
                *(const float4*)&eqb[(size_t)row * HH + hc + c4 * 4];
        }
        #pragma unroll
        for (int i = 0; i < 4; i++) {          // 128 x 64 ek tile (2048 f4)
            int f = tid + i * 512;
            int row = f >> 4, c4 = f & 15;
            *(float4*)&eks[row][c4 * 4] =
                *(const float4*)&ekb[(size_t)row * HH + hc + c4 * 4];
        }
        __syncthreads();

        for (int h0 = 0; h0 < 64; h0 += 4) {
            float4 wv4 = *(const float4*)&wv[hc + h0];   // uniform -> s_load
            float4 eq4[4], ek4[4];
            #pragma unroll
            for (int j = 0; j < 4; j++) eq4[j] = *(const float4*)&eqs[tq + 16 * j][h0];
            #pragma unroll
            for (int j = 0; j < 4; j++) ek4[j] = *(const float4*)&eks[tk + 32 * j][h0];
            #pragma unroll
            for (int jq = 0; jq < 4; jq++) {
                #pragma unroll
                for (int jk = 0; jk < 4; jk++) {
                    float u0 = fminf(fmaf(eq4[jq].x, ek4[jk].x, 1.0f), 3e7f);
                    float u1 = fminf(fmaf(eq4[jq].y, ek4[jk].y, 1.0f), 3e7f);
                    float u2 = fminf(fmaf(eq4[jq].z, ek4[jk].z, 1.0f), 3e7f);
                    float u3 = fminf(fmaf(eq4[jq].w, ek4[jk].w, 1.0f), 3e7f);
                    float p01 = u0 * u1, p23 = u2 * u3;
                    float n01 = fmaf(wv4.x, u1, wv4.y * u0);
                    float n23 = fmaf(wv4.z, u3, wv4.w * u2);
                    float N = fmaf(n01, p23, n23 * p01);
                    acc[jq][jk] = fmaf(N, rcp_fast(p01 * p23), acc[jq][jk]);
                }
            }
        }
    }

    const float CN = -2.8853900817779268f;  // -2*log2(e)
    ushort* ph = Phi + ((size_t)b * QS + q0) * KSZ + k0;
    ushort* pl = Plo + ((size_t)b * QS + q0) * KSZ + k0;
    #pragma unroll
    for (int jq = 0; jq < 4; jq++) {
        float rowp = 0.f;
        #pragma unroll
        for (int jk = 0; jk < 4; jk++) {
            float pv_ = exp2_fast(acc[jq][jk] * CN);
            ushort hh, ll; split1(pv_, hh, ll);
            size_t o = (size_t)(tq + 16 * jq) * KSZ + tk + 32 * jk;
            ph[o] = hh; pl[o] = ll;
            rowp += pv_;
        }
        // reduce across the 32 k-threads of this q-row (xor masks < 32 stay
        // within each 32-lane half of the wave)
        #pragma unroll
        for (int m = 16; m; m >>= 1) rowp += __shfl_xor(rowp, m);
        if ((tid & 31) == 0)
            rsp[((size_t)b * QS + q0 + tq + 16 * jq) * 8 + blockIdx.x] = rowp;
    }
}

// ---------------------------------------------------------------------------
// Kernel 4: out = P @ V / rowsum via MFMA, LDS-STAGED (confirmed ~19 us win
// in R11): coalesced 128B-segment global reads -> LDS (stride 68 ushort,
// b64 accesses = 2-way banks, free) -> fragment reads -> 3 MFMAs/k16.
// Block = 64m x 64n, 4 waves = 2x2 of 32x32, 16 K-chunks of 64, register
// prefetch of chunk c+1. 256 blocks, XCD swizzle.
// ---------------------------------------------------------------------------
__global__ __launch_bounds__(256) void pv_mfma_kernel(
    const ushort* __restrict__ Phi, const ushort* __restrict__ Plo,
    const ushort* __restrict__ vhi, const ushort* __restrict__ vlo,
    const float* __restrict__ rsp, float* __restrict__ outp)
{
    __shared__ ushort PhS[64][68];
    __shared__ ushort PlS[64][68];
    __shared__ ushort VhS[64][68];
    __shared__ ushort VlS[64][68];
    __shared__ float invs[64];

    const int id  = blockIdx.x;         // 256 blocks
    const int x   = id & 7;             // ~XCD
    const int g   = id >> 3;            // 0..31
    const int bmg = x * 4 + (g >> 3);   // 0..31
    const int b   = bmg >> 3, mt = bmg & 7;   // 64-row m-tile
    const int ntB = g & 7;                    // 64-col n-tile

    const int tid = threadIdx.x, w = tid >> 6, lane = tid & 63;
    const int col = lane & 31, kg = lane >> 5;

    if (tid < 64) {
        const float* rp = rsp + ((size_t)b * QS + mt * 64 + tid) * 8;
        float s = 0.f;
        #pragma unroll
        for (int i = 0; i < 8; i++) s += rp[i];
        invs[tid] = rcp_fast(s);
    }

    const int wm = (w & 1) * 32, wn = (w >> 1) * 32;

    // staging: thread -> row sr (0..63), 32B at short-offset cc
    const int sr = tid >> 2, cc = (tid & 3) * 16;
    const ushort* gPh = Phi + ((size_t)b * QS  + mt * 64 + sr) * KSZ + cc;
    const ushort* gPl = Plo + ((size_t)b * QS  + mt * 64 + sr) * KSZ + cc;
    const ushort* gVh = vhi + ((size_t)b * DVV + ntB * 64 + sr) * KSZ + cc;
    const ushort* gVl = vlo + ((size_t)b * DVV + ntB * 64 + sr) * KSZ + cc;

    f32x16 acc;
    #pragma unroll
    for (int i = 0; i < 16; i++) acc[i] = 0.f;

    uint4 rph0, rph1, rpl0, rpl1, rvh0, rvh1, rvl0, rvl1;
#define LOADC(kc) \
    rph0 = *(const uint4*)(gPh + (kc)); rph1 = *(const uint4*)(gPh + (kc) + 8); \
    rpl0 = *(const uint4*)(gPl + (kc)); rpl1 = *(const uint4*)(gPl + (kc) + 8); \
    rvh0 = *(const uint4*)(gVh + (kc)); rvh1 = *(const uint4*)(gVh + (kc) + 8); \
    rvl0 = *(const uint4*)(gVl + (kc)); rvl1 = *(const uint4*)(gVl + (kc) + 8);
#define STOREC() { \
    ull* dPh = (ull*)&PhS[sr][cc]; ull* dPl = (ull*)&PlS[sr][cc]; \
    ull* dVh = (ull*)&VhS[sr][cc]; ull* dVl = (ull*)&VlS[sr][cc]; \
    dPh[0] = ((ull*)&rph0)[0]; dPh[1] = ((ull*)&rph0)[1]; \
    dPh[2] = ((ull*)&rph1)[0]; dPh[3] = ((ull*)&rph1)[1]; \
    dPl[0] = ((ull*)&rpl0)[0]; dPl[1] = ((ull*)&rpl0)[1]; \
    dPl[2] = ((ull*)&rpl1)[0]; dPl[3] = ((ull*)&rpl1)[1]; \
    dVh[0] = ((ull*)&rvh0)[0]; dVh[1] = ((ull*)&rvh0)[1]; \
    dVh[2] = ((ull*)&rvh1)[0]; dVh[3] = ((ull*)&rvh1)[1]; \
    dVl[0] = ((ull*)&rvl0)[0]; dVl[1] = ((ull*)&rvl0)[1]; \
    dVl[2] = ((ull*)&rvl1)[0]; dVl[3] = ((ull*)&rvl1)[1]; }

    LOADC(0);
    STOREC();
    __syncthreads();

    for (int c = 0; c < 16; c++) {
        if (c < 15) { LOADC((c + 1) * 64); }
        #pragma unroll
        for (int kk = 0; kk < 4; kk++) {
            const int off = kk * 16 + kg * 8;
            short8 ah, al, vh, vl;
            { const ull* p = (const ull*)&PhS[wm + col][off];
              ((ull*)&ah)[0] = p[0]; ((ull*)&ah)[1] = p[1]; }
            { const ull* p = (const ull*)&PlS[wm + col][off];
              ((ull*)&al)[0] = p[0]; ((ull*)&al)[1] = p[1]; }
            { const ull* p = (const ull*)&VhS[wn + col][off];
              ((ull*)&vh)[0] = p[0]; ((ull*)&vh)[1] = p[1]; }
            { const ull* p = (const ull*)&VlS[wn + col][off];
              ((ull*)&vl)[0] = p[0]; ((ull*)&vl)[1] = p[1]; }
            acc = __builtin_amdgcn_mfma_f32_32x32x16_bf16(ah, vh, acc, 0, 0, 0);
            acc = __builtin_amdgcn_mfma_f32_32x32x16_bf16(ah, vl, acc, 0, 0, 0);
            acc = __builtin_amdgcn_mfma_f32_32x32x16_bf16(al, vh, acc, 0, 0, 0);
        }
        __syncthreads();                 // all waves done reading this chunk
        if (c < 15) { STOREC(); __syncthreads(); }
    }

    // C/D layout: col = lane&31, row = (r&3) + 8*(r>>2) + 4*kg
    float* ob = outp + ((size_t)b * QS + mt * 64 + wm) * DVV + ntB * 64 + wn;
    #pragma unroll
    for (int r = 0; r < 16; r++) {
        const int rb = (r & 3) + 8 * (r >> 2) + 4 * kg;
        ob[(size_t)rb * DVV + col] = acc[r] * invs[wm + rb];
    }
#undef LOADC
#undef STOREC
}

// ---------------------------------------------------------------------------
extern "C" void kernel_launch(void* const* d_in, const int* in_sizes, int n_in,
                              void* d_out, int out_size, void* d_ws, size_t ws_size,
                              hipStream_t stream)
{
    const float* queries = (const float*)d_in[0];
    const float* keys    = (const float*)d_in[1];
    const float* values  = (const float*)d_in[2];
    const float* Wq      = (const float*)d_in[3];
    const float* Wk      = (const float*)d_in[4];
    const float* wv      = (const float*)d_in[5];
    float* out = (float*)d_out;

    // float region
    float*  eq  = (float*)d_ws;
    float*  ek  = eq + (size_t)BB * QS * HH;
    float*  rsp = ek + (size_t)BB * KSZ * HH;
    // ushort region
    ushort* Phi = (ushort*)(rsp + (size_t)BB * QS * 8);
    ushort* Plo = Phi + (size_t)BB * QS * KSZ;
    ushort* vhi = Plo + (size_t)BB * QS * KSZ;
    ushort* vlo = vhi + (size_t)BB * KSZ * DVV;
    ushort* qh  = vlo + (size_t)BB * KSZ * DVV;
    ushort* ql  = qh  + (size_t)BB * QS * DD;
    ushort* kh  = ql  + (size_t)BB * QS * DD;
    ushort* kl  = kh  + (size_t)BB * KSZ * DD;
    ushort* wqh = kl  + (size_t)BB * KSZ * DD;
    ushort* wql = wqh + (size_t)HH * DD;
    ushort* wkh = wql + (size_t)HH * DD;
    ushort* wkl = wkh + (size_t)HH * DD;

    split_kernel<<<dim3(NSQ + NSK + NWT), 256, 0, stream>>>(
        queries, keys, Wq, Wk, qh, ql, kh, kl, wqh, wql, wkh, wkl);

    projvt_kernel<<<dim3(NPJ + NVT), 256, 0, stream>>>(
        qh, ql, kh, kl, wqh, wql, wkh, wkl, values, eq, ek, vhi, vlo);

    scores_kernel<<<dim3(KSZ / 128, QS / 64, BB), 512, 0, stream>>>(
        eq, ek, wv, Phi, Plo, rsp);

    pv_mfma_kernel<<<dim3(256), 256, 0, stream>>>(Phi, Plo, vhi, vlo, rsp, out);
}

// Round 13
// 146.315 us; speedup vs baseline: 1.5643x; 1.0100x over previous
//
#include <hip/hip_runtime.h>

#define BB   4
#define QS   512
#define KSZ  1024
#define DD   512
#define HH   128
#define DVV  512

typedef unsigned int uint;
typedef unsigned short ushort;
typedef unsigned long long ull;
typedef __attribute__((ext_vector_type(8)))  short short8;   // 8 bf16 (4 VGPRs)
typedef __attribute__((ext_vector_type(16))) float f32x16;   // MFMA 32x32 acc

__device__ __forceinline__ float rcp_fast(float x)  { return __builtin_amdgcn_rcpf(x); }
__device__ __forceinline__ float exp2_fast(float x) { return __builtin_amdgcn_exp2f(x); }

// split fp32 -> bf16 hi (truncate) + bf16 lo (residual); ~2^-17 rel combined
__device__ __forceinline__ void split1(float v, ushort& h, ushort& l) {
    uint u = __float_as_uint(v);
    h = (ushort)(u >> 16);
    float r = v - __uint_as_float(u & 0xffff0000u);
    l = (ushort)(__float_as_uint(r) >> 16);
}

// split_kernel grid segments (q/k/W only; V^T lives in projvt_kernel)
#define NSQ  (BB * QS * DD / 4 / 256)     // 1024
#define NSK  (BB * KSZ * DD / 4 / 256)    // 2048
#define NWT  128                          // 64 per W
#define NPJ  192                          // proj blocks (768 waves)
#define NVT  (BB * (KSZ / 32) * (DVV / 32))  // 2048 V-transpose blocks

// ---------------------------------------------------------------------------
// Kernel 1: bf16 pre-split of q, k (element-wise) and W_q/W_k (transpose to
// [h][d]). Pure memory-bound, ~25 MB.
// ---------------------------------------------------------------------------
__global__ __launch_bounds__(256) void split_kernel(
    const float* __restrict__ q, const float* __restrict__ k,
    const float* __restrict__ Wq, const float* __restrict__ Wk,
    ushort* __restrict__ qh, ushort* __restrict__ ql,
    ushort* __restrict__ kh, ushort* __restrict__ kl,
    ushort* __restrict__ wqh, ushort* __restrict__ wql,
    ushort* __restrict__ wkh, ushort* __restrict__ wkl)
{
    const int id  = blockIdx.x;
    const int tid = threadIdx.x;

    if (id < NSQ + NSK) {
        const float* src; ushort* dh; ushort* dl; size_t i;
        if (id < NSQ) { src = q; dh = qh; dl = ql; i = (size_t)id * 256 + tid; }
        else          { src = k; dh = kh; dl = kl; i = (size_t)(id - NSQ) * 256 + tid; }
        float4 v = ((const float4*)src)[i];
        ushort h0,h1,h2,h3,l0,l1,l2,l3;
        split1(v.x,h0,l0); split1(v.y,h1,l1); split1(v.z,h2,l2); split1(v.w,h3,l3);
        *(ushort4*)&dh[i * 4] = make_ushort4(h0,h1,h2,h3);
        *(ushort4*)&dl[i * 4] = make_ushort4(l0,l1,l2,l3);
        return;
    }
    // ---- W transpose + split: [512][128] -> [128][512] hi/lo ----
    __shared__ float Ts[32][33];
    int t = id - (NSQ + NSK);
    const float* W; ushort* dh; ushort* dl;
    if (t < 64) { W = Wq; dh = wqh; dl = wql; }
    else        { W = Wk; dh = wkh; dl = wkl; t -= 64; }
    const int d0 = (t >> 2) * 32, h0 = (t & 3) * 32;
    {
        const int dd = tid >> 3, c4 = (tid & 7) * 4;
        float4 v = *(const float4*)&W[(size_t)(d0 + dd) * HH + h0 + c4];
        Ts[dd][c4 + 0] = v.x; Ts[dd][c4 + 1] = v.y;
        Ts[dd][c4 + 2] = v.z; Ts[dd][c4 + 3] = v.w;
    }
    __syncthreads();
    {
        const int hh = tid >> 3, d4 = (tid & 7) * 4;
        ushort h[4], l[4];
        #pragma unroll
        for (int i = 0; i < 4; i++) split1(Ts[d4 + i][hh], h[i], l[i]);
        size_t o = (size_t)(h0 + hh) * DD + d0 + d4;
        *(ushort4*)&dh[o] = make_ushort4(h[0], h[1], h[2], h[3]);
        *(ushort4*)&dl[o] = make_ushort4(l[0], l[1], l[2], l[3]);
    }
}

// ---------------------------------------------------------------------------
// Kernel 2 (fused): blocks [0,NPJ) = projection via MFMA (pre-split bf16
// operands, b128 loads, 3 MFMAs/k16) + exp(2x). Blocks [NPJ,+NVT) = V
// transpose+split (memory-bound backfill behind proj's 192-block tail).
// ---------------------------------------------------------------------------
__global__ __launch_bounds__(256) void projvt_kernel(
    const ushort* __restrict__ qh, const ushort* __restrict__ ql,
    const ushort* __restrict__ kh, const ushort* __restrict__ kl,
    const ushort* __restrict__ wqh, const ushort* __restrict__ wql,
    const ushort* __restrict__ wkh, const ushort* __restrict__ wkl,
    const float* __restrict__ val,
    float* __restrict__ eq, float* __restrict__ ek,
    ushort* __restrict__ vhi, ushort* __restrict__ vlo)
{
    const int id  = blockIdx.x;
    const int tid = threadIdx.x;

    if (id >= NPJ) {
        __shared__ float Ts[32][33];
        const int t   = id - NPJ;
        const int b   = t >> 9;
        const int rem = t & 511;
        const int k0  = (rem >> 4) * 32;
        const int n0  = (rem & 15) * 32;
        {
            const int kk = tid >> 3, n4 = (tid & 7) * 4;
            float4 v = *(const float4*)&val[((size_t)b * KSZ + k0 + kk) * DVV + n0 + n4];
            Ts[kk][n4 + 0] = v.x; Ts[kk][n4 + 1] = v.y;
            Ts[kk][n4 + 2] = v.z; Ts[kk][n4 + 3] = v.w;
        }
        __syncthreads();
        {
            const int nn = tid >> 3, k4 = (tid & 7) * 4;
            ushort h[4], l[4];
            #pragma unroll
            for (int i = 0; i < 4; i++) split1(Ts[k4 + i][nn], h[i], l[i]);
            size_t o = ((size_t)b * DVV + n0 + nn) * KSZ + k0 + k4;
            *(ushort4*)&vhi[o] = make_ushort4(h[0], h[1], h[2], h[3]);
            *(ushort4*)&vlo[o] = make_ushort4(l[0], l[1], l[2], l[3]);
        }
        return;
    }

    // ---- projection: eq/ek[m][h] = exp2(C2L * sum_d A[m][d]*W[d][h]) ----
    const int w = tid >> 6, lane = tid & 63;
    const int row = lane & 31, kg = lane >> 5;
    const int gw = id * 4 + w;                  // 0..767

    const ushort *pa_h, *pa_l, *pb_h, *pb_l; float* op; int m0, nt;
    if (gw < 256) {
        m0 = (gw >> 2) * 32; nt = gw & 3;
        pa_h = qh; pa_l = ql; pb_h = wqh; pb_l = wql; op = eq;
    } else {
        const int g = gw - 256;
        m0 = (g >> 2) * 32; nt = g & 3;
        pa_h = kh; pa_l = kl; pb_h = wkh; pb_l = wkl; op = ek;
    }

    const ushort* ah_p = pa_h + (size_t)(m0 + row) * DD + kg * 8;
    const ushort* al_p = pa_l + (size_t)(m0 + row) * DD + kg * 8;
    const ushort* bh_p = pb_h + (size_t)(nt * 32 + row) * DD + kg * 8;
    const ushort* bl_p = pb_l + (size_t)(nt * 32 + row) * DD + kg * 8;

    f32x16 acc;
    #pragma unroll
    for (int i = 0; i < 16; i++) acc[i] = 0.f;

    #pragma unroll 8
    for (int ks = 0; ks < DD; ks += 16) {
        short8 ah = *(const short8*)(ah_p + ks);
        short8 al = *(const short8*)(al_p + ks);
        short8 bh = *(const short8*)(bh_p + ks);
        short8 bl = *(const short8*)(bl_p + ks);
        acc = __builtin_amdgcn_mfma_f32_32x32x16_bf16(ah, bh, acc, 0, 0, 0);
        acc = __builtin_amdgcn_mfma_f32_32x32x16_bf16(ah, bl, acc, 0, 0, 0);
        acc = __builtin_amdgcn_mfma_f32_32x32x16_bf16(al, bh, acc, 0, 0, 0);
    }

    const float C2L = 2.8853900817779268f;  // 2*log2(e)
    float* ob = op + (size_t)m0 * HH + nt * 32;
    #pragma unroll
    for (int r = 0; r < 16; r++) {
        const int rb = (r & 3) + 8 * (r >> 2) + 4 * kg;
        ob[(size_t)rb * HH + row] = exp2_fast(acc[r] * C2L);
    }
}

// ---------------------------------------------------------------------------
// Kernel 3: P = exp(-2 * sum_h w_v[h]/(eq*ek+1)) as bf16 hi/lo + rsp partials
// (32 per row, k-tiles of 32). Tile 64q x 32k, 256 threads, thread tile
// 4q x 2k -> GRID 1024 blocks = 4 independent blocks/CU (26.1 KB LDS each,
// 16 waves/CU): barrier stalls of one block overlap with compute of others.
// (R10 measured 33.9us at 2 blocks/CU; R12's 1-block/CU retile was slower.)
// ---------------------------------------------------------------------------
__global__ __launch_bounds__(256) void scores_kernel(
    const float* __restrict__ eq, const float* __restrict__ ek,
    const float* __restrict__ wv, ushort* __restrict__ Phi,
    ushort* __restrict__ Plo, float* __restrict__ rsp)
{
    __shared__ float eqs[64][68];
    __shared__ float eks[32][68];

    const int tid = threadIdx.x;
    const int b  = blockIdx.z;
    const int q0 = blockIdx.y * 64;
    const int k0 = blockIdx.x * 32;

    const float* eqb = eq + ((size_t)b * QS  + q0) * HH;
    const float* ekb = ek + ((size_t)b * KSZ + k0) * HH;

    const int tk = tid & 15;    // k rows tk + 16*jk (jk<2)
    const int tq = tid >> 4;    // q rows tq + 16*jq (jq<4)

    float acc[4][2] = {};

    for (int hc = 0; hc < HH; hc += 64) {
        __syncthreads();
        #pragma unroll
        for (int i = 0; i < 4; i++) {          // 64 x 64 eq tile (1024 f4)
            int f = tid + i * 256;
            int row = f >> 4, c4 = f & 15;
            *(float4*)&eqs[row][c4 * 4] =
                *(const float4*)&eqb[(size_t)row * HH + hc + c4 * 4];
        }
        #pragma unroll
        for (int i = 0; i < 2; i++) {          // 32 x 64 ek tile (512 f4)
            int f = tid + i * 256;
            int row = f >> 4, c4 = f & 15;
            *(float4*)&eks[row][c4 * 4] =
                *(const float4*)&ekb[(size_t)row * HH + hc + c4 * 4];
        }
        __syncthreads();

        for (int h0 = 0; h0 < 64; h0 += 4) {
            float4 wv4 = *(const float4*)&wv[hc + h0];   // uniform -> s_load
            float4 eq4[4], ek4[2];
            #pragma unroll
            for (int j = 0; j < 4; j++) eq4[j] = *(const float4*)&eqs[tq + 16 * j][h0];
            #pragma unroll
            for (int j = 0; j < 2; j++) ek4[j] = *(const float4*)&eks[tk + 16 * j][h0];
            #pragma unroll
            for (int jq = 0; jq < 4; jq++) {
                #pragma unroll
                for (int jk = 0; jk < 2; jk++) {
                    float u0 = fminf(fmaf(eq4[jq].x, ek4[jk].x, 1.0f), 3e7f);
                    float u1 = fminf(fmaf(eq4[jq].y, ek4[jk].y, 1.0f), 3e7f);
                    float u2 = fminf(fmaf(eq4[jq].z, ek4[jk].z, 1.0f), 3e7f);
                    float u3 = fminf(fmaf(eq4[jq].w, ek4[jk].w, 1.0f), 3e7f);
                    float p01 = u0 * u1, p23 = u2 * u3;
                    float n01 = fmaf(wv4.x, u1, wv4.y * u0);
                    float n23 = fmaf(wv4.z, u3, wv4.w * u2);
                    float N = fmaf(n01, p23, n23 * p01);
                    acc[jq][jk] = fmaf(N, rcp_fast(p01 * p23), acc[jq][jk]);
                }
            }
        }
    }

    const float CN = -2.8853900817779268f;  // -2*log2(e)
    ushort* ph = Phi + ((size_t)b * QS + q0) * KSZ + k0;
    ushort* pl = Plo + ((size_t)b * QS + q0) * KSZ + k0;
    #pragma unroll
    for (int jq = 0; jq < 4; jq++) {
        float rowp = 0.f;
        #pragma unroll
        for (int jk = 0; jk < 2; jk++) {
            float pv_ = exp2_fast(acc[jq][jk] * CN);
            ushort hh, ll; split1(pv_, hh, ll);
            size_t o = (size_t)(tq + 16 * jq) * KSZ + tk + 16 * jk;
            ph[o] = hh; pl[o] = ll;
            rowp += pv_;
        }
        // reduce across the 16 k-threads (consecutive lanes, masks 1..8)
        #pragma unroll
        for (int m = 8; m; m >>= 1) rowp += __shfl_xor(rowp, m);
        if ((tid & 15) == 0)
            rsp[((size_t)b * QS + q0 + tq + 16 * jq) * 32 + blockIdx.x] = rowp;
    }
}

// ---------------------------------------------------------------------------
// Kernel 4: out = P @ V / rowsum via MFMA, LDS-STAGED (confirmed ~19 us win
// in R11): coalesced 128B-segment global reads -> LDS (stride 68 ushort,
// b64 accesses = 2-way banks, free) -> fragment reads -> 3 MFMAs/k16.
// Block = 64m x 64n, 4 waves = 2x2 of 32x32, 16 K-chunks of 64, register
// prefetch of chunk c+1. 256 blocks, XCD swizzle.
// ---------------------------------------------------------------------------
__global__ __launch_bounds__(256) void pv_mfma_kernel(
    const ushort* __restrict__ Phi, const ushort* __restrict__ Plo,
    const ushort* __restrict__ vhi, const ushort* __restrict__ vlo,
    const float* __restrict__ rsp, float* __restrict__ outp)
{
    __shared__ ushort PhS[64][68];
    __shared__ ushort PlS[64][68];
    __shared__ ushort VhS[64][68];
    __shared__ ushort VlS[64][68];
    __shared__ float invs[64];

    const int id  = blockIdx.x;         // 256 blocks
    const int x   = id & 7;             // ~XCD
    const int g   = id >> 3;            // 0..31
    const int bmg = x * 4 + (g >> 3);   // 0..31
    const int b   = bmg >> 3, mt = bmg & 7;   // 64-row m-tile
    const int ntB = g & 7;                    // 64-col n-tile

    const int tid = threadIdx.x, w = tid >> 6, lane = tid & 63;
    const int col = lane & 31, kg = lane >> 5;

    if (tid < 64) {
        const float* rp = rsp + ((size_t)b * QS + mt * 64 + tid) * 32;
        float s = 0.f;
        #pragma unroll
        for (int i = 0; i < 8; i++) {
            float4 v = *(const float4*)(rp + i * 4);
            s += v.x + v.y + v.z + v.w;
        }
        invs[tid] = rcp_fast(s);
    }

    const int wm = (w & 1) * 32, wn = (w >> 1) * 32;

    // staging: thread -> row sr (0..63), 32B at short-offset cc
    const int sr = tid >> 2, cc = (tid & 3) * 16;
    const ushort* gPh = Phi + ((size_t)b * QS  + mt * 64 + sr) * KSZ + cc;
    const ushort* gPl = Plo + ((size_t)b * QS  + mt * 64 + sr) * KSZ + cc;
    const ushort* gVh = vhi + ((size_t)b * DVV + ntB * 64 + sr) * KSZ + cc;
    const ushort* gVl = vlo + ((size_t)b * DVV + ntB * 64 + sr) * KSZ + cc;

    f32x16 acc;
    #pragma unroll
    for (int i = 0; i < 16; i++) acc[i] = 0.f;

    uint4 rph0, rph1, rpl0, rpl1, rvh0, rvh1, rvl0, rvl1;
#define LOADC(kc) \
    rph0 = *(const uint4*)(gPh + (kc)); rph1 = *(const uint4*)(gPh + (kc) + 8); \
    rpl0 = *(const uint4*)(gPl + (kc)); rpl1 = *(const uint4*)(gPl + (kc) + 8); \
    rvh0 = *(const uint4*)(gVh + (kc)); rvh1 = *(const uint4*)(gVh + (kc) + 8); \
    rvl0 = *(const uint4*)(gVl + (kc)); rvl1 = *(const uint4*)(gVl + (kc) + 8);
#define STOREC() { \
    ull* dPh = (ull*)&PhS[sr][cc]; ull* dPl = (ull*)&PlS[sr][cc]; \
    ull* dVh = (ull*)&VhS[sr][cc]; ull* dVl = (ull*)&VlS[sr][cc]; \
    dPh[0] = ((ull*)&rph0)[0]; dPh[1] = ((ull*)&rph0)[1]; \
    dPh[2] = ((ull*)&rph1)[0]; dPh[3] = ((ull*)&rph1)[1]; \
    dPl[0] = ((ull*)&rpl0)[0]; dPl[1] = ((ull*)&rpl0)[1]; \
    dPl[2] = ((ull*)&rpl1)[0]; dPl[3] = ((ull*)&rpl1)[1]; \
    dVh[0] = ((ull*)&rvh0)[0]; dVh[1] = ((ull*)&rvh0)[1]; \
    dVh[2] = ((ull*)&rvh1)[0]; dVh[3] = ((ull*)&rvh1)[1]; \
    dVl[0] = ((ull*)&rvl0)[0]; dVl[1] = ((ull*)&rvl0)[1]; \
    dVl[2] = ((ull*)&rvl1)[0]; dVl[3] = ((ull*)&rvl1)[1]; }

    LOADC(0);
    STOREC();
    __syncthreads();

    for (int c = 0; c < 16; c++) {
        if (c < 15) { LOADC((c + 1) * 64); }
        #pragma unroll
        for (int kk = 0; kk < 4; kk++) {
            const int off = kk * 16 + kg * 8;
            short8 ah, al, vh, vl;
            { const ull* p = (const ull*)&PhS[wm + col][off];
              ((ull*)&ah)[0] = p[0]; ((ull*)&ah)[1] = p[1]; }
            { const ull* p = (const ull*)&PlS[wm + col][off];
              ((ull*)&al)[0] = p[0]; ((ull*)&al)[1] = p[1]; }
            { const ull* p = (const ull*)&VhS[wn + col][off];
              ((ull*)&vh)[0] = p[0]; ((ull*)&vh)[1] = p[1]; }
            { const ull* p = (const ull*)&VlS[wn + col][off];
              ((ull*)&vl)[0] = p[0]; ((ull*)&vl)[1] = p[1]; }
            acc = __builtin_amdgcn_mfma_f32_32x32x16_bf16(ah, vh, acc, 0, 0, 0);
            acc = __builtin_amdgcn_mfma_f32_32x32x16_bf16(ah, vl, acc, 0, 0, 0);
            acc = __builtin_amdgcn_mfma_f32_32x32x16_bf16(al, vh, acc, 0, 0, 0);
        }
        __syncthreads();                 // all waves done reading this chunk
        if (c < 15) { STOREC(); __syncthreads(); }
    }

    // C/D layout: col = lane&31, row = (r&3) + 8*(r>>2) + 4*kg
    float* ob = outp + ((size_t)b * QS + mt * 64 + wm) * DVV + ntB * 64 + wn;
    #pragma unroll
    for (int r = 0; r < 16; r++) {
        const int rb = (r & 3) + 8 * (r >> 2) + 4 * kg;
        ob[(size_t)rb * DVV + col] = acc[r] * invs[wm + rb];
    }
#undef LOADC
#undef STOREC
}

// ---------------------------------------------------------------------------
extern "C" void kernel_launch(void* const* d_in, const int* in_sizes, int n_in,
                              void* d_out, int out_size, void* d_ws, size_t ws_size,
                              hipStream_t stream)
{
    const float* queries = (const float*)d_in[0];
    const float* keys    = (const float*)d_in[1];
    const float* values  = (const float*)d_in[2];
    const float* Wq      = (const float*)d_in[3];
    const float* Wk      = (const float*)d_in[4];
    const float* wv      = (const float*)d_in[5];
    float* out = (float*)d_out;

    // float region
    float*  eq  = (float*)d_ws;
    float*  ek  = eq + (size_t)BB * QS * HH;
    float*  rsp = ek + (size_t)BB * KSZ * HH;     // 32 partials/row now
    // ushort region
    ushort* Phi = (ushort*)(rsp + (size_t)BB * QS * 32);
    ushort* Plo = Phi + (size_t)BB * QS * KSZ;
    ushort* vhi = Plo + (size_t)BB * QS * KSZ;
    ushort* vlo = vhi + (size_t)BB * KSZ * DVV;
    ushort* qh  = vlo + (size_t)BB * KSZ * DVV;
    ushort* ql  = qh  + (size_t)BB * QS * DD;
    ushort* kh  = ql  + (size_t)BB * QS * DD;
    ushort* kl  = kh  + (size_t)BB * KSZ * DD;
    ushort* wqh = kl  + (size_t)BB * KSZ * DD;
    ushort* wql = wqh + (size_t)HH * DD;
    ushort* wkh = wql + (size_t)HH * DD;
    ushort* wkl = wkh + (size_t)HH * DD;

    split_kernel<<<dim3(NSQ + NSK + NWT), 256, 0, stream>>>(
        queries, keys, Wq, Wk, qh, ql, kh, kl, wqh, wql, wkh, wkl);

    projvt_kernel<<<dim3(NPJ + NVT), 256, 0, stream>>>(
        qh, ql, kh, kl, wqh, wql, wkh, wkl, values, eq, ek, vhi, vlo);

    scores_kernel<<<dim3(KSZ / 32, QS / 64, BB), 256, 0, stream>>>(
        eq, ek, wv, Phi, Plo, rsp);

    pv_mfma_kernel<<<dim3(256), 256, 0, stream>>>(Phi, Plo, vhi, vlo, rsp, out);
}